// Round 17
// baseline (3448.852 us; speedup 1.0000x reference)
//
#include <hip/hip_runtime.h>
#include <math.h>

#define T_STEPS 4096
#define NB 16          // batch
#define NH 256         // hidden
#define BH (NB * NH)   // 4096 floats per time step
#define DT_STEP 0.1f
#define T_PROBE 1024   // probe scans: quarter length

typedef __attribute__((ext_vector_type(8))) short short8;
typedef __attribute__((ext_vector_type(4))) float f32x4;

// ---------------- expm via Taylor series ----------------
__global__ __launch_bounds__(1024) void k_init_S(const float* __restrict__ A,
                                                 float* __restrict__ S) {
    int idx = blockIdx.x * 1024 + threadIdx.x;
    int i = idx >> 8, j = idx & 255;
    S[idx] = A[idx] + (i == j ? 1.0f : 0.0f);
}

__global__ __launch_bounds__(256) void k_expm_term(const float* __restrict__ Pprev,
                                                   const float* __restrict__ A,
                                                   float* __restrict__ Pnew,
                                                   float* __restrict__ S,
                                                   float invk) {
    __shared__ float prow[256];
    int i = blockIdx.x, j = threadIdx.x;
    prow[j] = Pprev[i * 256 + j];
    __syncthreads();
    float acc = 0.f;
#pragma unroll 8
    for (int m = 0; m < 256; ++m) acc = fmaf(prow[m], A[m * 256 + j], acc);
    float v = acc * invk;
    Pnew[i * 256 + j] = v;
    S[i * 256 + j] += v;
}

// ---------------- pack BOTH weight matrices into bf16 B-frag-linear (one launch) ----
__global__ __launch_bounds__(64) void k_pack_b2(const float* __restrict__ W0,
                                                const float* __restrict__ W1,
                                                unsigned int* __restrict__ P0,
                                                unsigned int* __restrict__ P1) {
    const int f = blockIdx.x & 127;
    const float* W = (blockIdx.x >> 7) ? W1 : W0;
    unsigned int* P = (blockIdx.x >> 7) ? P1 : P0;
    const int l = threadIdx.x;
    const int n  = ((f >> 3) << 4) | (l & 15);
    const int k0 = ((f & 7) << 5) | ((l >> 4) << 3);
    const float* sp = W + n * 256 + k0;
    unsigned int o0, o1, o2, o3;
    asm volatile("v_cvt_pk_bf16_f32 %0, %1, %2" : "=v"(o0) : "v"(sp[0]), "v"(sp[1]));
    asm volatile("v_cvt_pk_bf16_f32 %0, %1, %2" : "=v"(o1) : "v"(sp[2]), "v"(sp[3]));
    asm volatile("v_cvt_pk_bf16_f32 %0, %1, %2" : "=v"(o2) : "v"(sp[4]), "v"(sp[5]));
    asm volatile("v_cvt_pk_bf16_f32 %0, %1, %2" : "=v"(o3) : "v"(sp[6]), "v"(sp[7]));
    uint4* dst = (uint4*)(P + ((size_t)f * 64 + l) * 4);
    *dst = make_uint4(o0, o1, o2, o3);
}

// ---------------- MFMA GEMM: C[M x 256] = A[M x 256] @ W^T + bias (unchanged) ----------------
__global__ __launch_bounds__(256) void k_gemm_mfma(const float* A,   // no restrict: may alias C
                                                   const unsigned int* __restrict__ P,
                                                   const float* __restrict__ bias,
                                                   float* C) {
    const int tid = threadIdx.x;
    const int w = tid >> 6, l = tid & 63;
    const size_t r0 = (size_t)blockIdx.x * 64 + w * 16;
    const int arow = l & 15;
    const int kg   = l >> 4;

    union Frag { unsigned int u[4]; uint4 q; short8 v; };

    Frag af[8];
    const float* ap = A + (r0 + arow) * 256 + kg * 8;
#pragma unroll
    for (int kt = 0; kt < 8; ++kt) {
        float4 x0 = *(const float4*)(ap + kt * 32);
        float4 x1 = *(const float4*)(ap + kt * 32 + 4);
        asm volatile("v_cvt_pk_bf16_f32 %0, %1, %2" : "=v"(af[kt].u[0]) : "v"(x0.x), "v"(x0.y));
        asm volatile("v_cvt_pk_bf16_f32 %0, %1, %2" : "=v"(af[kt].u[1]) : "v"(x0.z), "v"(x0.w));
        asm volatile("v_cvt_pk_bf16_f32 %0, %1, %2" : "=v"(af[kt].u[2]) : "v"(x1.x), "v"(x1.y));
        asm volatile("v_cvt_pk_bf16_f32 %0, %1, %2" : "=v"(af[kt].u[3]) : "v"(x1.z), "v"(x1.w));
    }

    f32x4 acc[16];
#pragma unroll
    for (int nt = 0; nt < 16; ++nt) acc[nt] = f32x4{0.f, 0.f, 0.f, 0.f};

#pragma unroll
    for (int nt = 0; nt < 16; ++nt) {
#pragma unroll
        for (int kt = 0; kt < 8; ++kt) {
            Frag bf_;
            bf_.q = *(const uint4*)(P + (size_t)(((nt << 3) | kt) * 64 + l) * 4);
            acc[nt] = __builtin_amdgcn_mfma_f32_16x16x32_bf16(af[kt].v, bf_.v, acc[nt], 0, 0, 0);
        }
    }

#pragma unroll
    for (int nt = 0; nt < 16; ++nt) {
        float b = bias[(nt << 4) | arow];
        float* cp = C + (r0 + kg * 4) * 256 + (nt << 4) + arow;
#pragma unroll
        for (int r = 0; r < 4; ++r)
            cp[(size_t)r * 256] = acc[nt][r] + b;
    }
}

// ---------------- MFMA scan v7 (byte-identical to round 14/15 best, 1786 us) ----------------
__global__ __launch_bounds__(512)
__attribute__((amdgpu_waves_per_eu(2, 2)))
void k_scan_bc6(const float* __restrict__ u,
                const float* S,        // Wexp (f32); no restrict
                float* hidden,
                float* __restrict__ hfin) {
    const int b   = blockIdx.x;
    const int tid = threadIdx.x;
    const int w   = tid >> 6;           // wave 0..7: n-tiles 2w, 2w+1
    const int l   = tid & 63;
    const int lg  = l >> 4;             // k-group 0..3
    const int lr  = l & 15;             // row within n-tile

    __shared__ unsigned int hlds[256];  // 2 x 512B: h as bf16, linear, dbuf
    char* lds = (char*)hlds;

    union Frag { unsigned int u[4]; short8 v; };

    Frag ef[2][8];
#pragma unroll
    for (int j = 0; j < 2; ++j) {
        const int n = ((2 * w + j) << 4) | lr;
#pragma unroll
        for (int kt = 0; kt < 8; ++kt) {
            const int k0 = kt * 32 + lg * 8;
            const float* sp = S + (size_t)n * 256 + k0;
            float e[8];
#pragma unroll
            for (int q = 0; q < 8; ++q)
                e[q] = sp[q] - ((n == k0 + q) ? 1.0f : 0.0f);
#pragma unroll
            for (int r2 = 0; r2 < 4; ++r2) {
                unsigned int pk;
                asm volatile("v_cvt_pk_bf16_f32 %0, %1, %2"
                             : "=v"(pk) : "v"(e[2 * r2]), "v"(e[2 * r2 + 1]));
                ef[j][kt].u[r2] = pk;
            }
        }
    }

    const int j_own = (l >> 2) & 1;
    const int n_own = ((2 * w + j_own) << 4) | ((l >> 4) << 2) | (l & 3);
    const bool st = ((l & 8) == 0);
    const bool wrt = ((l & 9) == 0);

    if (tid < 256) hlds[tid] = 0u;

    const int NBLK = T_STEPS / 8;
    const size_t blkstride = 8 * (size_t)BH;

    float* hst = hidden + (size_t)b * NH + n_own;
    const float* uld = u + (size_t)b * NH + n_own + blkstride;

    float ucur[8], unxt[8], hsav[8];
    {
        const float* up0 = u + (size_t)b * NH + n_own;
#pragma unroll
        for (int q = 0; q < 8; ++q) ucur[q] = up0[q * (size_t)BH];
    }
    float hval = 0.f;
    __syncthreads();

    int roff = 0;
    for (int blk = 0; blk < NBLK; ++blk) {
#pragma unroll
        for (int s = 0; s < 8; ++s) {
            if (s == 0) {
                if (blk) {
#pragma unroll
                    for (int q = 0; q < 8; ++q)
                        if (st) hst[q * (size_t)BH] = hsav[q];
                }
#pragma unroll
                for (int q = 0; q < 8; ++q) unxt[q] = uld[q * (size_t)BH];
            }

            Frag hb[8];
#pragma unroll
            for (int kt = 0; kt < 8; ++kt)
                hb[kt].v = *(const short8*)(lds + roff + kt * 64 + lg * 16);

            f32x4 a0 = {0,0,0,0}, a1 = {0,0,0,0};
#pragma unroll
            for (int kt = 0; kt < 8; ++kt) {
                a0 = __builtin_amdgcn_mfma_f32_16x16x32_bf16(ef[0][kt].v, hb[kt].v, a0, 0, 0, 0);
                a1 = __builtin_amdgcn_mfma_f32_16x16x32_bf16(ef[1][kt].v, hb[kt].v, a1, 0, 0, 0);
            }

            f32x4 c = j_own ? a1 : a0;
            float y01 = (l & 1) ? c[1] : c[0];
            float y23 = (l & 1) ? c[3] : c[2];
            float y   = (l & 2) ? y23 : y01;

            float xa = (ucur[s] - hval) - y;
            float E2 = __expf(2.0f * xa);
            float th = fmaf(-2.0f, __builtin_amdgcn_rcpf(E2 + 1.0f), 1.0f);
            hval = fmaf(DT_STEP, th, hval);
            hsav[s] = hval;

            int nb = __builtin_amdgcn_mov_dpp(__float_as_int(hval), 0xB1, 0xF, 0xF, true);
            if (wrt) {
                unsigned int pk;
                asm volatile("v_cvt_pk_bf16_f32 %0, %1, %2"
                             : "=v"(pk) : "v"(hval), "v"(__int_as_float(nb)));
                *(unsigned int*)(lds + (roff ^ 512) + ((n_own >> 1) << 2)) = pk;
            }
            roff ^= 512;
            __syncthreads();
        }
#pragma unroll
        for (int q = 0; q < 8; ++q) ucur[q] = unxt[q];
        if (blk) hst += blkstride;
        if (blk <= NBLK - 3) uld += blkstride;
    }

#pragma unroll
    for (int q = 0; q < 8; ++q)
        if (st) hst[q * (size_t)BH] = hsav[q];
    if (st) hfin[(size_t)b * NH + n_own] = hval;
}

// ---------------- ablation probes: bc6 @1024 steps with one phase removed ----------------
// MODE bit 1: skip barrier | bit 2: half the ds_reads | bit 4: skip MFMA.
// Output -> dead scratch (sink). Separate kernels so production codegen is
// untouched; hb kept live through y->hval->store (rule #17).
template <int MODE>
__global__ __launch_bounds__(512)
__attribute__((amdgpu_waves_per_eu(2, 2)))
void k_probe(const float* __restrict__ u,
             const float* S,
             float* sink) {
    const int b   = blockIdx.x;
    const int tid = threadIdx.x;
    const int w   = tid >> 6;
    const int l   = tid & 63;
    const int lg  = l >> 4;
    const int lr  = l & 15;

    __shared__ unsigned int hlds[256];
    char* lds = (char*)hlds;

    union Frag { unsigned int u[4]; short8 v; };

    Frag ef[2][8];
#pragma unroll
    for (int j = 0; j < 2; ++j) {
        const int n = ((2 * w + j) << 4) | lr;
#pragma unroll
        for (int kt = 0; kt < 8; ++kt) {
            const int k0 = kt * 32 + lg * 8;
            const float* sp = S + (size_t)n * 256 + k0;
            float e[8];
#pragma unroll
            for (int q = 0; q < 8; ++q)
                e[q] = sp[q] - ((n == k0 + q) ? 1.0f : 0.0f);
#pragma unroll
            for (int r2 = 0; r2 < 4; ++r2) {
                unsigned int pk;
                asm volatile("v_cvt_pk_bf16_f32 %0, %1, %2"
                             : "=v"(pk) : "v"(e[2 * r2]), "v"(e[2 * r2 + 1]));
                ef[j][kt].u[r2] = pk;
            }
        }
    }

    const int j_own = (l >> 2) & 1;
    const int n_own = ((2 * w + j_own) << 4) | ((l >> 4) << 2) | (l & 3);
    const bool st = ((l & 8) == 0);
    const bool wrt = ((l & 9) == 0);

    if (tid < 256) hlds[tid] = 0u;

    const int NBLK = T_PROBE / 8;
    const size_t blkstride = 8 * (size_t)BH;

    float* hst = sink + (size_t)b * NH + n_own;
    const float* uld = u + (size_t)b * NH + n_own + blkstride;

    float ucur[8], unxt[8], hsav[8];
    {
        const float* up0 = u + (size_t)b * NH + n_own;
#pragma unroll
        for (int q = 0; q < 8; ++q) ucur[q] = up0[q * (size_t)BH];
    }
    float hval = 0.f;
    __syncthreads();

    int roff = 0;
    for (int blk = 0; blk < NBLK; ++blk) {
#pragma unroll
        for (int s = 0; s < 8; ++s) {
            if (s == 0) {
                if (blk) {
#pragma unroll
                    for (int q = 0; q < 8; ++q)
                        if (st) hst[q * (size_t)BH] = hsav[q];
                }
#pragma unroll
                for (int q = 0; q < 8; ++q) unxt[q] = uld[q * (size_t)BH];
            }

            Frag hb[8];
            if (MODE & 2) {
#pragma unroll
                for (int kt = 0; kt < 4; ++kt)
                    hb[kt].v = *(const short8*)(lds + roff + kt * 64 + lg * 16);
#pragma unroll
                for (int kt = 4; kt < 8; ++kt) hb[kt] = hb[kt - 4];
            } else {
#pragma unroll
                for (int kt = 0; kt < 8; ++kt)
                    hb[kt].v = *(const short8*)(lds + roff + kt * 64 + lg * 16);
            }

            f32x4 a0, a1;
            if (MODE & 4) {
                // MFMA stubbed; keep hb live through y
                a0 = f32x4{__int_as_float(hb[0].u[0]), __int_as_float(hb[1].u[1]),
                           __int_as_float(hb[2].u[2]), __int_as_float(hb[3].u[3])};
                a1 = f32x4{__int_as_float(hb[4].u[0]), __int_as_float(hb[5].u[1]),
                           __int_as_float(hb[6].u[2]), __int_as_float(hb[7].u[3])};
            } else {
                a0 = f32x4{0.f, 0.f, 0.f, 0.f};
                a1 = f32x4{0.f, 0.f, 0.f, 0.f};
#pragma unroll
                for (int kt = 0; kt < 8; ++kt) {
                    a0 = __builtin_amdgcn_mfma_f32_16x16x32_bf16(ef[0][kt].v, hb[kt].v, a0, 0, 0, 0);
                    a1 = __builtin_amdgcn_mfma_f32_16x16x32_bf16(ef[1][kt].v, hb[kt].v, a1, 0, 0, 0);
                }
            }

            f32x4 c = j_own ? a1 : a0;
            float y01 = (l & 1) ? c[1] : c[0];
            float y23 = (l & 1) ? c[3] : c[2];
            float y   = (l & 2) ? y23 : y01;

            float xa = (ucur[s] - hval) - y;
            float E2 = __expf(2.0f * xa);
            float th = fmaf(-2.0f, __builtin_amdgcn_rcpf(E2 + 1.0f), 1.0f);
            hval = fmaf(DT_STEP, th, hval);
            hsav[s] = hval;

            int nb = __builtin_amdgcn_mov_dpp(__float_as_int(hval), 0xB1, 0xF, 0xF, true);
            if (wrt) {
                unsigned int pk;
                asm volatile("v_cvt_pk_bf16_f32 %0, %1, %2"
                             : "=v"(pk) : "v"(hval), "v"(__int_as_float(nb)));
                *(unsigned int*)(lds + (roff ^ 512) + ((n_own >> 1) << 2)) = pk;
            }
            roff ^= 512;
            if (!(MODE & 1)) __syncthreads();
        }
#pragma unroll
        for (int q = 0; q < 8; ++q) ucur[q] = unxt[q];
        if (blk) hst += blkstride;
        if (blk <= NBLK - 3) uld += blkstride;
    }

#pragma unroll
    for (int q = 0; q < 8; ++q)
        if (st) hst[q * (size_t)BH] = hsav[q];
}

extern "C" void kernel_launch(void* const* d_in, const int* in_sizes, int n_in,
                              void* d_out, int out_size, void* d_ws, size_t ws_size,
                              hipStream_t stream) {
    const float* x     = (const float*)d_in[0];  // [T,B,D]
    const float* U_w   = (const float*)d_in[1];  // [H,D]
    const float* U_b   = (const float*)d_in[2];  // [H]
    const float* W_log = (const float*)d_in[3];  // [H,H]
    const float* c_w   = (const float*)d_in[4];  // [O,H]
    const float* c_b   = (const float*)d_in[5];  // [O]

    float* out    = (float*)d_out;
    float* hidden = out;                          // stage hidden in d_out, then in-place GEMM
    float* hfin   = out + (long)T_STEPS * BH;     // second output chunk

    float* ws = (float*)d_ws;
    float* S  = ws;                // 65536 floats: Wexp accumulator
    float* Pa = ws + 65536;        // expm scratch; reused as packed U_w (bf16 frags)
    float* Pb = ws + 2 * 65536;    // expm scratch; reused as packed c_w (bf16 frags)
    float* u  = ws + 3 * 65536;    // 16,777,216 floats

    // Wexp = expm(W_log), Taylor K=6 (||W_log||_2 ~ 0.32 -> remainder ~1e-7 << bf16 eps)
    k_init_S<<<64, 1024, 0, stream>>>(W_log, S);
    const float* prev = W_log;
    float* cur = Pa;
    for (int k = 2; k <= 6; ++k) {
        k_expm_term<<<256, 256, 0, stream>>>(prev, W_log, cur, S, 1.0f / (float)k);
        prev = cur;
        cur = (cur == Pa) ? Pb : Pa;
    }

    // pack both weights into bf16 B-frag-linear layout (one launch)
    unsigned int* PUw = (unsigned int*)Pa;
    unsigned int* Pcw = (unsigned int*)Pb;
    k_pack_b2<<<256, 64, 0, stream>>>(U_w, c_w, PUw, Pcw);

    // u = x @ U_w^T + U_b   (bf16 MFMA, f32 accumulate/output)
    k_gemm_mfma<<<1024, 256, 0, stream>>>(x, PUw, U_b, u);

    // sequential recurrence (8-step VMEM batching), hidden -> d_out
    k_scan_bc6<<<NB, 512, 0, stream>>>(u, S, hidden, hfin);

    // out = hidden @ c_w^T + c_b, in place (bf16 MFMA)
    k_gemm_mfma<<<1024, 256, 0, stream>>>(hidden, Pcw, c_b, hidden);

    // ---- ablation probes (outputs to dead scratch; u is recomputed each call) ----
    float* sink = u + 8 * 1024 * 1024;   // second half of u region (dead)
    k_probe<0><<<NB, 512, 0, stream>>>(u, S, sink);
    k_probe<1><<<NB, 512, 0, stream>>>(u, S, sink);
    k_probe<2><<<NB, 512, 0, stream>>>(u, S, sink);
    k_probe<4><<<NB, 512, 0, stream>>>(u, S, sink);
}

// Round 18
// 1910.379 us; speedup vs baseline: 1.8053x; 1.8053x over previous
//
#include <hip/hip_runtime.h>
#include <math.h>

#define T_STEPS 4096
#define NB 16          // batch
#define NH 256         // hidden
#define BH (NB * NH)   // 4096 floats per time step
#define DT_STEP 0.1f

typedef __attribute__((ext_vector_type(8))) short short8;
typedef __attribute__((ext_vector_type(4))) float f32x4;

// ---------------- expm via Taylor series ----------------
// Pnew = (Pprev @ A) * invk ; S (+)= Pnew.  INIT folds S = I + A + Pnew
// into the first term launch (k=2), eliminating the separate init kernel.
template <bool INIT>
__global__ __launch_bounds__(256) void k_expm_term(const float* __restrict__ Pprev,
                                                   const float* __restrict__ A,
                                                   float* __restrict__ Pnew,
                                                   float* __restrict__ S,
                                                   float invk) {
    __shared__ float prow[256];
    int i = blockIdx.x, j = threadIdx.x;
    prow[j] = Pprev[i * 256 + j];
    __syncthreads();
    float acc = 0.f;
#pragma unroll 8
    for (int m = 0; m < 256; ++m) acc = fmaf(prow[m], A[m * 256 + j], acc);
    float v = acc * invk;
    Pnew[i * 256 + j] = v;
    if (INIT)
        S[i * 256 + j] = (i == j ? 1.0f : 0.0f) + A[i * 256 + j] + v;
    else
        S[i * 256 + j] += v;
}

// ---------------- pack BOTH weight matrices into bf16 B-frag-linear (one launch) ----
__global__ __launch_bounds__(64) void k_pack_b2(const float* __restrict__ W0,
                                                const float* __restrict__ W1,
                                                unsigned int* __restrict__ P0,
                                                unsigned int* __restrict__ P1) {
    const int f = blockIdx.x & 127;
    const float* W = (blockIdx.x >> 7) ? W1 : W0;
    unsigned int* P = (blockIdx.x >> 7) ? P1 : P0;
    const int l = threadIdx.x;
    const int n  = ((f >> 3) << 4) | (l & 15);
    const int k0 = ((f & 7) << 5) | ((l >> 4) << 3);
    const float* sp = W + n * 256 + k0;
    unsigned int o0, o1, o2, o3;
    asm volatile("v_cvt_pk_bf16_f32 %0, %1, %2" : "=v"(o0) : "v"(sp[0]), "v"(sp[1]));
    asm volatile("v_cvt_pk_bf16_f32 %0, %1, %2" : "=v"(o1) : "v"(sp[2]), "v"(sp[3]));
    asm volatile("v_cvt_pk_bf16_f32 %0, %1, %2" : "=v"(o2) : "v"(sp[4]), "v"(sp[5]));
    asm volatile("v_cvt_pk_bf16_f32 %0, %1, %2" : "=v"(o3) : "v"(sp[6]), "v"(sp[7]));
    uint4* dst = (uint4*)(P + ((size_t)f * 64 + l) * 4);
    *dst = make_uint4(o0, o1, o2, o3);
}

// ---------------- MFMA GEMM: C[M x 256] = A[M x 256] @ W^T + bias ----------------
__global__ __launch_bounds__(256) void k_gemm_mfma(const float* A,   // no restrict: may alias C
                                                   const unsigned int* __restrict__ P,
                                                   const float* __restrict__ bias,
                                                   float* C) {
    const int tid = threadIdx.x;
    const int w = tid >> 6, l = tid & 63;
    const size_t r0 = (size_t)blockIdx.x * 64 + w * 16;
    const int arow = l & 15;
    const int kg   = l >> 4;

    union Frag { unsigned int u[4]; uint4 q; short8 v; };

    Frag af[8];
    const float* ap = A + (r0 + arow) * 256 + kg * 8;
#pragma unroll
    for (int kt = 0; kt < 8; ++kt) {
        float4 x0 = *(const float4*)(ap + kt * 32);
        float4 x1 = *(const float4*)(ap + kt * 32 + 4);
        asm volatile("v_cvt_pk_bf16_f32 %0, %1, %2" : "=v"(af[kt].u[0]) : "v"(x0.x), "v"(x0.y));
        asm volatile("v_cvt_pk_bf16_f32 %0, %1, %2" : "=v"(af[kt].u[1]) : "v"(x0.z), "v"(x0.w));
        asm volatile("v_cvt_pk_bf16_f32 %0, %1, %2" : "=v"(af[kt].u[2]) : "v"(x1.x), "v"(x1.y));
        asm volatile("v_cvt_pk_bf16_f32 %0, %1, %2" : "=v"(af[kt].u[3]) : "v"(x1.z), "v"(x1.w));
    }

    f32x4 acc[16];
#pragma unroll
    for (int nt = 0; nt < 16; ++nt) acc[nt] = f32x4{0.f, 0.f, 0.f, 0.f};

#pragma unroll
    for (int nt = 0; nt < 16; ++nt) {
#pragma unroll
        for (int kt = 0; kt < 8; ++kt) {
            Frag bf_;
            bf_.q = *(const uint4*)(P + (size_t)(((nt << 3) | kt) * 64 + l) * 4);
            acc[nt] = __builtin_amdgcn_mfma_f32_16x16x32_bf16(af[kt].v, bf_.v, acc[nt], 0, 0, 0);
        }
    }

#pragma unroll
    for (int nt = 0; nt < 16; ++nt) {
        float b = bias[(nt << 4) | arow];
        float* cp = C + (r0 + kg * 4) * 256 + (nt << 4) + arow;
#pragma unroll
        for (int r = 0; r < 4; ++r)
            cp[(size_t)r * 256] = acc[nt][r] + b;
    }
}

// ---------------- MFMA scan v7 (byte-identical to the 1786-us best) ----------------
// y = E@h (E = Wexp - I bf16 A-operand; h broadcast as B across 16 cols).
// 8 waves (2/SIMD): wave w owns n-tiles 2w, 2w+1; depth-8 SrcC chains.
// 8-step VMEM batching: 7 of 8 barriers drain an empty VMEM queue.
__global__ __launch_bounds__(512)
__attribute__((amdgpu_waves_per_eu(2, 2)))
void k_scan_bc6(const float* __restrict__ u,
                const float* S,        // Wexp (f32); no restrict
                float* hidden,
                float* __restrict__ hfin) {
    const int b   = blockIdx.x;
    const int tid = threadIdx.x;
    const int w   = tid >> 6;           // wave 0..7: n-tiles 2w, 2w+1
    const int l   = tid & 63;
    const int lg  = l >> 4;             // k-group 0..3
    const int lr  = l & 15;             // row within n-tile

    __shared__ unsigned int hlds[256];  // 2 x 512B: h as bf16, linear, dbuf
    char* lds = (char*)hlds;

    union Frag { unsigned int u[4]; short8 v; };

    Frag ef[2][8];
#pragma unroll
    for (int j = 0; j < 2; ++j) {
        const int n = ((2 * w + j) << 4) | lr;
#pragma unroll
        for (int kt = 0; kt < 8; ++kt) {
            const int k0 = kt * 32 + lg * 8;
            const float* sp = S + (size_t)n * 256 + k0;
            float e[8];
#pragma unroll
            for (int q = 0; q < 8; ++q)
                e[q] = sp[q] - ((n == k0 + q) ? 1.0f : 0.0f);
#pragma unroll
            for (int r2 = 0; r2 < 4; ++r2) {
                unsigned int pk;
                asm volatile("v_cvt_pk_bf16_f32 %0, %1, %2"
                             : "=v"(pk) : "v"(e[2 * r2]), "v"(e[2 * r2 + 1]));
                ef[j][kt].u[r2] = pk;
            }
        }
    }

    const int j_own = (l >> 2) & 1;
    const int n_own = ((2 * w + j_own) << 4) | ((l >> 4) << 2) | (l & 3);
    const bool st = ((l & 8) == 0);
    const bool wrt = ((l & 9) == 0);

    if (tid < 256) hlds[tid] = 0u;

    const int NBLK = T_STEPS / 8;
    const size_t blkstride = 8 * (size_t)BH;

    float* hst = hidden + (size_t)b * NH + n_own;
    const float* uld = u + (size_t)b * NH + n_own + blkstride;

    float ucur[8], unxt[8], hsav[8];
    {
        const float* up0 = u + (size_t)b * NH + n_own;
#pragma unroll
        for (int q = 0; q < 8; ++q) ucur[q] = up0[q * (size_t)BH];
    }
    float hval = 0.f;
    __syncthreads();

    int roff = 0;
    for (int blk = 0; blk < NBLK; ++blk) {
#pragma unroll
        for (int s = 0; s < 8; ++s) {
            if (s == 0) {
                if (blk) {
#pragma unroll
                    for (int q = 0; q < 8; ++q)
                        if (st) hst[q * (size_t)BH] = hsav[q];
                }
#pragma unroll
                for (int q = 0; q < 8; ++q) unxt[q] = uld[q * (size_t)BH];
            }

            Frag hb[8];
#pragma unroll
            for (int kt = 0; kt < 8; ++kt)
                hb[kt].v = *(const short8*)(lds + roff + kt * 64 + lg * 16);

            f32x4 a0 = {0,0,0,0}, a1 = {0,0,0,0};
#pragma unroll
            for (int kt = 0; kt < 8; ++kt) {
                a0 = __builtin_amdgcn_mfma_f32_16x16x32_bf16(ef[0][kt].v, hb[kt].v, a0, 0, 0, 0);
                a1 = __builtin_amdgcn_mfma_f32_16x16x32_bf16(ef[1][kt].v, hb[kt].v, a1, 0, 0, 0);
            }

            f32x4 c = j_own ? a1 : a0;
            float y01 = (l & 1) ? c[1] : c[0];
            float y23 = (l & 1) ? c[3] : c[2];
            float y   = (l & 2) ? y23 : y01;

            float xa = (ucur[s] - hval) - y;
            float E2 = __expf(2.0f * xa);
            float th = fmaf(-2.0f, __builtin_amdgcn_rcpf(E2 + 1.0f), 1.0f);
            hval = fmaf(DT_STEP, th, hval);
            hsav[s] = hval;

            int nb = __builtin_amdgcn_mov_dpp(__float_as_int(hval), 0xB1, 0xF, 0xF, true);
            if (wrt) {
                unsigned int pk;
                asm volatile("v_cvt_pk_bf16_f32 %0, %1, %2"
                             : "=v"(pk) : "v"(hval), "v"(__int_as_float(nb)));
                *(unsigned int*)(lds + (roff ^ 512) + ((n_own >> 1) << 2)) = pk;
            }
            roff ^= 512;
            __syncthreads();
        }
#pragma unroll
        for (int q = 0; q < 8; ++q) ucur[q] = unxt[q];
        if (blk) hst += blkstride;
        if (blk <= NBLK - 3) uld += blkstride;
    }

#pragma unroll
    for (int q = 0; q < 8; ++q)
        if (st) hst[q * (size_t)BH] = hsav[q];
    if (st) hfin[(size_t)b * NH + n_own] = hval;
}

extern "C" void kernel_launch(void* const* d_in, const int* in_sizes, int n_in,
                              void* d_out, int out_size, void* d_ws, size_t ws_size,
                              hipStream_t stream) {
    const float* x     = (const float*)d_in[0];  // [T,B,D]
    const float* U_w   = (const float*)d_in[1];  // [H,D]
    const float* U_b   = (const float*)d_in[2];  // [H]
    const float* W_log = (const float*)d_in[3];  // [H,H]
    const float* c_w   = (const float*)d_in[4];  // [O,H]
    const float* c_b   = (const float*)d_in[5];  // [O]

    float* out    = (float*)d_out;
    float* hidden = out;                          // stage hidden in d_out, then in-place GEMM
    float* hfin   = out + (long)T_STEPS * BH;     // second output chunk

    float* ws = (float*)d_ws;
    float* S  = ws;                // 65536 floats: Wexp accumulator
    float* Pa = ws + 65536;        // expm scratch; reused as packed U_w (bf16 frags)
    float* Pb = ws + 2 * 65536;    // expm scratch; reused as packed c_w (bf16 frags)
    float* u  = ws + 3 * 65536;    // 16,777,216 floats

    // Wexp = expm(W_log), Taylor K=5 (||W_log||_2 ~ 0.37 -> remainder ~4e-6 << bf16 eps).
    // First term launch also initializes S = I + A + A^2/2 (fused init).
    k_expm_term<true><<<256, 256, 0, stream>>>(W_log, W_log, Pa, S, 0.5f);
    k_expm_term<false><<<256, 256, 0, stream>>>(Pa, W_log, Pb, S, 1.0f / 3.0f);
    k_expm_term<false><<<256, 256, 0, stream>>>(Pb, W_log, Pa, S, 1.0f / 4.0f);
    k_expm_term<false><<<256, 256, 0, stream>>>(Pa, W_log, Pb, S, 1.0f / 5.0f);

    // pack both weights into bf16 B-frag-linear layout (one launch; Pa/Pb dead)
    unsigned int* PUw = (unsigned int*)Pa;
    unsigned int* Pcw = (unsigned int*)Pb;
    k_pack_b2<<<256, 64, 0, stream>>>(U_w, c_w, PUw, Pcw);

    // u = x @ U_w^T + U_b   (bf16 MFMA, f32 accumulate/output)
    k_gemm_mfma<<<1024, 256, 0, stream>>>(x, PUw, U_b, u);

    // sequential recurrence (8-step VMEM batching), hidden -> d_out
    k_scan_bc6<<<NB, 512, 0, stream>>>(u, S, hidden, hfin);

    // out = hidden @ c_w^T + c_b, in place (bf16 MFMA)
    k_gemm_mfma<<<1024, 256, 0, stream>>>(hidden, Pcw, c_b, hidden);
}